// Round 14
// baseline (53.384 us; speedup 1.0000x reference)
//
#include <hip/hip_runtime.h>
#include <math.h>

#define NB     24
#define FBIN   512
#define ROWS   (32*1200)
#define GRID   2048
#define BLK    256
#define WPB    4
#define NWAVES (GRID*WPB)    // 8192 waves; 4-5 rows each
#define SLOTS  36            // max 32 chunks/band (band 23) + pad; 144B stride, 16B-aligned
#define LOG2E  1.44269504f

__device__ __constant__ int   c_off[NB+1] = {0,3,6,9,12,16,20,24,29,34,40,47,55,64,74,86,100,118,140,169,204,246,304,384,512};
__device__ __constant__ float c_k[NB]     = {3,3,3,3,4,4,4,5,5,6,7,8,9,10,12,14,18,22,29,35,42,58,80,128};

#define RDLANE(v,i) __int_as_float(__builtin_amdgcn_readlane(__float_as_int(v), (i)))

__global__ __launch_bounds__(BLK) void pe_main(const float* __restrict__ lm,
                                               const float* __restrict__ re,
                                               const float* __restrict__ im,
                                               const float* __restrict__ S,
                                               float* __restrict__ partial)
{
    __shared__ float s_slot[WPB][2][NB*SLOTS];   // parity dbuf, 27.6 KB

    const int tid  = threadIdx.x;
    const int w    = tid >> 6;
    const int lane = tid & 63;

    // zero this wave's two slot buffers (pads stay 0 forever)
    {
        float* sw = &s_slot[w][0][0];
        for (int i = lane; i < 2*NB*SLOTS; i += 64) sw[i] = 0.f;
    }

    // ---- per-lane metadata: LANE-CONTIGUOUS layout ----
    // j=0..3 -> bins 4*lane+j (half 0); j=4..7 -> bins 256+4*lane+(j-4) (half 1)
    int waddr[8], band4[8];
    unsigned smask = 0;
    float rtq[8], a4[8];
    #pragma unroll
    for (int j = 0; j < 8; ++j) {
        const int binj  = (j < 4) ? (4*lane + j) : (256 + 4*lane + (j - 4));
        const int chunk = binj >> 2;              // = lane or lane+64
        int b = 0;
        for (int q = 0; q < NB; ++q) if (binj >= c_off[q+1]) b++;
        band4[j] = b << 2;
        waddr[j] = b*SLOTS + (chunk - (c_off[b] >> 2));
        if (j > 0 && waddr[j] == waddr[j-1]) smask |= 1u << j;
        const float z = (binj + 1) * 0.03125f;
        const float tqj = 3.64f*__builtin_amdgcn_exp2f(-0.8f*__builtin_amdgcn_logf(z + 1e-6f))
                        - 6.5f*__builtin_amdgcn_exp2f(-0.6f*LOG2E*(z-3.3f)*(z-3.3f))
                        + 1e-3f*z*z*z*z;
        a4[j] = 1.5f / c_k[b];            // 2/denom == rsqrt(a4 * t); weight = a4/57600
        // rsqrt(a4*max(t,tq)) == min(rsqrt(a4*t), rtq); tq<=0 never binds
        rtq[j] = (tqj > 0.f) ? __builtin_amdgcn_rsqf(a4[j] * tqj) : 3.4e38f;
    }

    // S column for my band (lanes 0-23) + 1/(colsum+eps), in registers
    const int cl = (lane < NB) ? lane : NB-1;
    float Sreg[NB];
    float colsum = 1e-8f;
    #pragma unroll
    for (int i = 0; i < NB; ++i) { Sreg[i] = S[i*NB + cl]; colsum += Sreg[i]; }
    const float invcol  = 1.0f / colsum;
    const float abandcl = 1.5f / c_k[cl];

    const int gw = blockIdx.x * WPB + w;
    const int e0 = 4*lane;           // element offset of half-0 float4
    const int e1 = 256 + 4*lane;     // element offset of half-1 float4
    size_t base = (size_t)gw * FBIN;
    const size_t step = (size_t)NWAVES * FBIN;

    // preload row 0 of ALL THREE streams (lane-contiguous)
    float4 L0 = *(const float4*)(lm + base + e0), L1 = *(const float4*)(lm + base + e1);
    float4 R0 = *(const float4*)(re + base + e0), R1 = *(const float4*)(re + base + e1);
    float4 I0 = *(const float4*)(im + base + e0), I1 = *(const float4*)(im + base + e1);

    float acc = 0.f;
    int par = 0;
    for (int row = gw; row < ROWS; row += NWAVES) {
        const float lmv[8] = {L0.x,L0.y,L0.z,L0.w,L1.x,L1.y,L1.z,L1.w};
        float sp[8];
        #pragma unroll
        for (int j = 0; j < 8; ++j)
            sp[j] = __builtin_amdgcn_exp2f(fminf(lmv[j], 10.f) * LOG2E);

        float* const slot = &s_slot[w][par][0];
        // branchless segmented stores: cumulative rewrite, last write per slot wins
        {
            float ps = sp[0];
            slot[waddr[0]] = ps;
            #pragma unroll
            for (int j = 1; j < 8; ++j) {
                ps = ((smask >> j) & 1u) ? ps + sp[j] : sp[j];
                slot[waddr[j]] = ps;
            }
        }

        // FULL next-row prefetch (all 3 streams), issued before the LDS drain
        const size_t nb = base + ((row + NWAVES < ROWS) ? step : (size_t)0);
        const float4 nL0 = *(const float4*)(lm + nb + e0), nL1 = *(const float4*)(lm + nb + e1);
        const float4 nR0 = *(const float4*)(re + nb + e0), nR1 = *(const float4*)(re + nb + e1);
        const float4 nI0 = *(const float4*)(im + nb + e0), nI1 = *(const float4*)(im + nb + e1);

        asm volatile("s_waitcnt lgkmcnt(0)" ::: "memory");   // own-wave store visibility

        // per-band sums (lanes 0-23): 9x b128 from zero-padded slots
        float psum_v = 0.f;
        if (lane < NB) {
            const float4* q = (const float4*)(slot + lane*SLOTS);
            float s0 = 0.f, s1 = 0.f, s2 = 0.f, s3 = 0.f;
            #pragma unroll
            for (int m = 0; m < 8; m += 4) {
                const float4 a = q[m+0], b = q[m+1], c = q[m+2], d = q[m+3];
                s0 += (a.x+a.y)+(a.z+a.w);
                s1 += (b.x+b.y)+(b.z+b.w);
                s2 += (c.x+c.y)+(c.z+c.w);
                s3 += (d.x+d.y)+(d.z+d.w);
            }
            const float4 e = q[8];
            psum_v = ((s0+s1)+(s2+s3)) + ((e.x+e.y)+(e.z+e.w));
        }

        // t = (psum@S + eps)*invcol; psum broadcast via readlane, S from registers;
        // one rsq per band: vb = rsqrt(a4_band * t)
        float vb;
        {
            float c0 = 1e-8f, c1 = 0.f, c2 = 0.f, c3 = 0.f;
            #pragma unroll
            for (int i = 0; i < NB; i += 4) {
                c0 = fmaf(RDLANE(psum_v,i+0), Sreg[i+0], c0);
                c1 = fmaf(RDLANE(psum_v,i+1), Sreg[i+1], c1);
                c2 = fmaf(RDLANE(psum_v,i+2), Sreg[i+2], c2);
                c3 = fmaf(RDLANE(psum_v,i+3), Sreg[i+3], c3);
            }
            const float tmine = ((c0+c1)+(c2+c3)) * invcol;
            vb = __builtin_amdgcn_rsqf(abandcl * tmine);
        }

        // broadcast vb[band] to all lanes via bpermute
        float vbb[8];
        #pragma unroll
        for (int j = 0; j < 8; ++j)
            vbb[j] = __int_as_float(__builtin_amdgcn_ds_bpermute(band4[j], __float_as_int(vb)));

        const float rv[8] = {R0.x,R0.y,R0.z,R0.w,R1.x,R1.y,R1.z,R1.w};
        const float iv[8] = {I0.x,I0.y,I0.z,I0.w,I1.x,I1.y,I1.z,I1.w};
        #pragma unroll
        for (int j = 0; j < 8; ++j) {
            const float u  = sp[j] * fminf(vbb[j], rtq[j]);   // == sp*rsqrt(a4*max(t,tq))
            const float pr = fmaf(fabsf(rv[j]), u, 1.0f);
            const float pi = fmaf(fabsf(iv[j]), u, 1.0f);
            acc = fmaf(__builtin_amdgcn_logf(pr * pi), a4[j], acc);
        }

        par ^= 1;                 // parity dbuf: no tail drain needed
        L0 = nL0; L1 = nL1; R0 = nR0; R1 = nR1; I0 = nI0; I1 = nI1;
        base += step;
    }

    #pragma unroll
    for (int o = 32; o > 0; o >>= 1) acc += __shfl_xor(acc, o, 64);
    if (lane == 0) partial[gw] = acc * (1.0f/57600.0f);
}

__global__ __launch_bounds__(256) void pe_final(const float* __restrict__ partial,
                                                float* __restrict__ out)
{
    __shared__ double sred[256];
    const int tid = threadIdx.x;
    double s = 0.0;
    for (int i = tid; i < NWAVES; i += 256) s += (double)partial[i];
    sred[tid] = s;
    __syncthreads();
    for (int k = 128; k > 0; k >>= 1) {
        if (tid < k) sred[tid] += sred[tid+k];
        __syncthreads();
    }
    if (tid == 0) out[0] = (float)(1.0 / (sred[0] + 1.0));
}

extern "C" void kernel_launch(void* const* d_in, const int* in_sizes, int n_in,
                              void* d_out, int out_size, void* d_ws, size_t ws_size,
                              hipStream_t stream) {
    const float* lm = (const float*)d_in[0];
    const float* re = (const float*)d_in[1];
    const float* im = (const float*)d_in[2];
    const float* S  = (const float*)d_in[3];
    float* partial = (float*)d_ws;   // NWAVES floats = 32 KB scratch
    pe_main<<<GRID, BLK, 0, stream>>>(lm, re, im, S, partial);
    pe_final<<<1, 256, 0, stream>>>(partial, (float*)d_out);
}